// Round 1
// baseline (76.464 us; speedup 1.0000x reference)
//
#include <hip/hip_runtime.h>
#include <hip/hip_bf16.h>

#define L_SEQ 1024
#define D_HEAD 64
#define QBLK 64
#define KVBLK 32
#define KSTR 72   // K tile LDS row stride (bf16 elems): 64 + 8 pad
#define VSTR 36   // V^T tile LDS row stride (bf16 elems): 32 + 4 pad

typedef __attribute__((ext_vector_type(8))) __bf16 bf16x8;
typedef __attribute__((ext_vector_type(4))) __bf16 bf16x4;
typedef __attribute__((ext_vector_type(4))) float f32x4;

// One block: one (batch, 64-row q-tile). 4 waves, each owns 16 q rows.
// Swapped QK^T: S^T = mfma(A=K_frag, B=Q_frag) so lane layout of S^T chunks
// feeds PV's A-operand (P) directly. Assumed A/B k-mapping
// g(h,e) = (e>>2)*16 + h*4 + (e&3) used consistently on both operands of both
// MFMAs -> correct for any true hardware k-order (bijection argument).
__global__ __launch_bounds__(256) void sdpa_fwd_kernel(
    const float* __restrict__ Q, const float* __restrict__ K,
    const float* __restrict__ V, float* __restrict__ O)
{
    __shared__ __bf16 kt[KVBLK * KSTR];   // K tile, row-major [32][KSTR]
    __shared__ __bf16 vt[D_HEAD * VSTR];  // V^T tile, [64][VSTR]

    const int tid  = threadIdx.x;
    const int lane = tid & 63;
    const int wave = tid >> 6;
    const int li   = lane & 15;   // q-row (col of S^T) / within-chunk kv row
    const int h    = lane >> 4;   // 0..3

    const int b     = blockIdx.x >> 4;   // 16 q-tiles per batch
    const int qtile = blockIdx.x & 15;
    const int qrow  = qtile * QBLK + wave * 16 + li;

    const float* Qb = Q + (size_t)b * L_SEQ * D_HEAD;
    const float* Kb = K + (size_t)b * L_SEQ * D_HEAD;
    const float* Vb = V + (size_t)b * L_SEQ * D_HEAD;

    // ---- Q fragments (B-operand): lane holds Q[qrow][d = g(h,e) + 32c] / 8
    bf16x8 qf[2];
    #pragma unroll
    for (int c = 0; c < 2; ++c) {
        #pragma unroll
        for (int hf = 0; hf < 2; ++hf) {
            f32x4 qv = *(const f32x4*)&Qb[(size_t)qrow * D_HEAD + c * 32 + hf * 16 + h * 4];
            #pragma unroll
            for (int j = 0; j < 4; ++j)
                qf[c][hf * 4 + j] = (__bf16)(qv[j] * 0.125f);  // fold 1/temperature
        }
    }

    f32x4 oacc[4];   // out^T accumulators: d-chunk dc -> O[qrow][dc*16 + 4h + r]
    #pragma unroll
    for (int dc = 0; dc < 4; ++dc) oacc[dc] = (f32x4){0.f, 0.f, 0.f, 0.f};
    float m_run = -1e30f;
    float l_run = 0.f;

    for (int kv = 0; kv < L_SEQ; kv += KVBLK) {
        __syncthreads();   // previous compute done before LDS overwrite

        // ---- stage K tile [32][64] f32 -> kt bf16 (coalesced float4 reads)
        #pragma unroll
        for (int it = 0; it < 2; ++it) {
            int idx = tid + it * 256;            // float4 index, 512 total
            int j   = idx >> 4;                  // kv row 0..31
            int d4  = (idx & 15) << 2;           // d 0..60
            f32x4 x = *(const f32x4*)&Kb[(size_t)(kv + j) * D_HEAD + d4];
            __bf16* dst = &kt[j * KSTR + d4];
            dst[0] = (__bf16)x[0]; dst[1] = (__bf16)x[1];
            dst[2] = (__bf16)x[2]; dst[3] = (__bf16)x[3];
        }
        // ---- stage V^T [64][32]: read V[j][d] float4, scatter to vt[d][j]
        #pragma unroll
        for (int it = 0; it < 2; ++it) {
            int idx = tid + it * 256;
            int j   = idx >> 4;
            int d4  = (idx & 15) << 2;
            f32x4 x = *(const f32x4*)&Vb[(size_t)(kv + j) * D_HEAD + d4];
            #pragma unroll
            for (int u = 0; u < 4; ++u)
                vt[(d4 + u) * VSTR + j] = (__bf16)x[u];
        }
        __syncthreads();

        // ---- S^T chunks: sacc[ch][r] = S[j = ch*16 + 4h + r][qrow] (already /8)
        f32x4 sacc[2];
        #pragma unroll
        for (int ch = 0; ch < 2; ++ch) {
            sacc[ch] = (f32x4){0.f, 0.f, 0.f, 0.f};
            #pragma unroll
            for (int c = 0; c < 2; ++c) {   // d-contraction halves
                bf16x8 kf;
                #pragma unroll
                for (int hf = 0; hf < 2; ++hf) {
                    bf16x4 k4 = *(const bf16x4*)&kt[(ch * 16 + li) * KSTR + c * 32 + hf * 16 + h * 4];
                    #pragma unroll
                    for (int j = 0; j < 4; ++j) kf[hf * 4 + j] = k4[j];
                }
                sacc[ch] = __builtin_amdgcn_mfma_f32_16x16x32_bf16(kf, qf[c], sacc[ch], 0, 0, 0);
            }
        }

        // ---- online softmax (row = q-row li; partners are lanes li+16k)
        float tmax = fmaxf(fmaxf(fmaxf(sacc[0][0], sacc[0][1]), fmaxf(sacc[0][2], sacc[0][3])),
                           fmaxf(fmaxf(sacc[1][0], sacc[1][1]), fmaxf(sacc[1][2], sacc[1][3])));
        tmax = fmaxf(tmax, __shfl_xor(tmax, 16, 64));
        tmax = fmaxf(tmax, __shfl_xor(tmax, 32, 64));
        const float m_new = fmaxf(m_run, tmax);
        const float scale = __expf(m_run - m_new);
        m_run = m_new;
        l_run *= scale;
        #pragma unroll
        for (int dc = 0; dc < 4; ++dc) {
            #pragma unroll
            for (int r = 0; r < 4; ++r) oacc[dc][r] *= scale;
        }

        bf16x8 pf;          // P fragment: elems (ch*4 + r) -> j = ch*16 + 4h + r
        float psum = 0.f;
        #pragma unroll
        for (int ch = 0; ch < 2; ++ch) {
            #pragma unroll
            for (int r = 0; r < 4; ++r) {
                float p = __expf(sacc[ch][r] - m_new);
                psum += p;
                pf[ch * 4 + r] = (__bf16)p;
            }
        }
        l_run += psum;      // per-lane partial; reduced after the loop

        // ---- PV: out^T[d][i] += V^T P, per 16-wide d chunk
        #pragma unroll
        for (int dc = 0; dc < 4; ++dc) {
            bf16x8 vf;      // A-operand: lane holds V[j = g(h,e)][d = dc*16 + li]
            #pragma unroll
            for (int hf = 0; hf < 2; ++hf) {
                bf16x4 v4 = *(const bf16x4*)&vt[(dc * 16 + li) * VSTR + hf * 16 + h * 4];
                #pragma unroll
                for (int j = 0; j < 4; ++j) vf[hf * 4 + j] = v4[j];
            }
            oacc[dc] = __builtin_amdgcn_mfma_f32_16x16x32_bf16(vf, pf, oacc[dc], 0, 0, 0);
        }
    }

    // ---- finalize
    l_run += __shfl_xor(l_run, 16, 64);
    l_run += __shfl_xor(l_run, 32, 64);
    const float inv_l = 1.f / l_run;

    float* Ob = O + ((size_t)b * L_SEQ + qrow) * D_HEAD;
    #pragma unroll
    for (int dc = 0; dc < 4; ++dc) {
        f32x4 ov;
        #pragma unroll
        for (int r = 0; r < 4; ++r) ov[r] = oacc[dc][r] * inv_l;
        *(f32x4*)&Ob[dc * 16 + h * 4] = ov;
    }
}

extern "C" void kernel_launch(void* const* d_in, const int* in_sizes, int n_in,
                              void* d_out, int out_size, void* d_ws, size_t ws_size,
                              hipStream_t stream) {
    const float* q = (const float*)d_in[0];
    const float* k = (const float*)d_in[1];
    const float* v = (const float*)d_in[2];
    float* o = (float*)d_out;

    const int B = 64;
    dim3 grid(B * (L_SEQ / QBLK));   // 1024 blocks: (batch, q-tile)
    dim3 block(256);
    sdpa_fwd_kernel<<<grid, block, 0, stream>>>(q, k, v, o);
}

// Round 2
// 54.679 us; speedup vs baseline: 1.3984x; 1.3984x over previous
//
#include <hip/hip_runtime.h>
#include <hip/hip_bf16.h>

#define L_SEQ 1024
#define D_HEAD 64
#define NT 32          // number of 32-row KV tiles
#define QBLK 64
#define KVBLK 32
#define KSTR 72
#define VSTR 36

typedef __attribute__((ext_vector_type(8))) __bf16 bf16x8;
typedef __attribute__((ext_vector_type(4))) __bf16 bf16x4;
typedef __attribute__((ext_vector_type(4))) float f32x4;
typedef unsigned int u32;

#define STAGE16(gsrc, ldst)                                                     \
  __builtin_amdgcn_global_load_lds(                                             \
      (const __attribute__((address_space(1))) u32*)(gsrc),                     \
      (__attribute__((address_space(3))) u32*)(ldst), 16, 0, 0)

// ---------------------------------------------------------------------------
// Pre-pass: f32 -> bf16, fold 1/temperature into Q, permute K/Q columns into
// fragment order, XOR-swizzle K tiles, transpose V into V^T tile images.
// Layouts (per 32-row KV tile = 4KB):
//   K_pre: [row][c''] c'' = (c32*32 + h*8 + hf*4 + j) ^ ((row&7)*8), stride 64
//   V_pre: [d][c']   c'  = h*8 + hf*4 + j  (k = hf*16 + h*4 + j), stride 32
//   Q_pre: [row][c']  c' = c32*32 + h*8 + hf*4 + j   (no swizzle), scaled 1/8
// ---------------------------------------------------------------------------
__global__ __launch_bounds__(256) void sdpa_prep(
    const float* __restrict__ Q, const float* __restrict__ K,
    const float* __restrict__ V, __bf16* __restrict__ Qp,
    __bf16* __restrict__ Kp, __bf16* __restrict__ Vp)
{
    const int gid = blockIdx.x * 256 + threadIdx.x;   // quad id, 3*2^20 total
    const int seg = gid >> 20;                        // 0:Q 1:K 2:V
    const int q   = gid & 0xFFFFF;
    const int row = q >> 4;                           // global row (b*1024 + r)
    const int d4  = (q & 15) << 2;

    if (seg == 0) {
        f32x4 x = *(const f32x4*)&Q[(size_t)row * 64 + d4];
        const int c32 = d4 >> 5, rem = d4 & 31, hf = rem >> 4, h = (rem & 15) >> 2;
        const int cp = c32 * 32 + h * 8 + hf * 4;
        bf16x4 o;
        #pragma unroll
        for (int u = 0; u < 4; ++u) o[u] = (__bf16)(x[u] * 0.125f);
        *(bf16x4*)&Qp[(size_t)row * 64 + cp] = o;
    } else if (seg == 1) {
        f32x4 x = *(const f32x4*)&K[(size_t)row * 64 + d4];
        const int c32 = d4 >> 5, rem = d4 & 31, hf = rem >> 4, h = (rem & 15) >> 2;
        const int cp = ((c32 * 32 + h * 8) ^ ((row & 7) * 8)) + hf * 4;
        bf16x4 o;
        #pragma unroll
        for (int u = 0; u < 4; ++u) o[u] = (__bf16)x[u];
        *(bf16x4*)&Kp[(size_t)row * 64 + cp] = o;
    } else {
        f32x4 x = *(const f32x4*)&V[(size_t)row * 64 + d4];
        const int k = row & 31;
        const int vhf = k >> 4, vh = (k & 15) >> 2, vj = k & 3;
        const int cp = vh * 8 + vhf * 4 + vj;
        const size_t tb = (size_t)(row >> 5) * 2048;   // V^T tile base (elems)
        #pragma unroll
        for (int u = 0; u < 4; ++u)
            Vp[tb + (size_t)(d4 + u) * 32 + cp] = (__bf16)x[u];
    }
}

// ---------------------------------------------------------------------------
// Main: triple-buffered LDS, global_load_lds staging, 1 barrier/iter, counted
// vmcnt, defer-max online softmax. One block = (batch, 64-row q-tile).
// ---------------------------------------------------------------------------
__global__ __launch_bounds__(256) void sdpa_main(
    const __bf16* __restrict__ Qp, const __bf16* __restrict__ Kp,
    const __bf16* __restrict__ Vp, float* __restrict__ O)
{
    __shared__ __align__(16) char ldsraw[3 * 8192];   // 3 bufs x (K 4KB + V 4KB)

    const int tid  = threadIdx.x;
    const int lane = tid & 63;
    const int wave = tid >> 6;
    const int li   = lane & 15;
    const int h    = lane >> 4;

    // XCD-chunked swizzle: XCD x gets logical blocks [x*128, x*128+128) ->
    // batches 8x..8x+7 resident in one L2 (2MB of K/V bf16).
    const int wg     = blockIdx.x;
    const int lb     = (wg & 7) * 128 + (wg >> 3);
    const int b      = lb >> 4;
    const int qt     = lb & 15;
    const int qrow   = qt * QBLK + wave * 16 + li;

    const char* Kb = (const char*)(Kp + (size_t)b * L_SEQ * 64);
    const char* Vb = (const char*)(Vp + (size_t)b * L_SEQ * 64);
    const __bf16* Qb = Qp + ((size_t)b * L_SEQ + qrow) * 64;

    const bf16x8 qf0 = *(const bf16x8*)&Qb[h * 8];
    const bf16x8 qf1 = *(const bf16x8*)&Qb[32 + h * 8];

    f32x4 oacc0 = {0.f,0.f,0.f,0.f}, oacc1 = {0.f,0.f,0.f,0.f};
    f32x4 oacc2 = {0.f,0.f,0.f,0.f}, oacc3 = {0.f,0.f,0.f,0.f};
    float m_run = -1e30f, l_run = 0.f;

    auto stage = [&](int t, int bi) {
        const size_t go = (size_t)t * 4096 + (size_t)wave * 1024 + (size_t)(lane << 4);
        STAGE16(Kb + go, ldsraw + bi * 8192 + wave * 1024);
        STAGE16(Vb + go, ldsraw + bi * 8192 + 4096 + wave * 1024);
    };

    auto body = [&](int bi) {
        const char* bb  = ldsraw + bi * 8192;
        const int   swz = (li & 7) << 4;
        // K fragments: ds_read_b128, swizzled -> conflict-free
        bf16x8 kf00 = *(const bf16x8*)(bb + li * 128 + ((h * 16) ^ swz));
        bf16x8 kf01 = *(const bf16x8*)(bb + li * 128 + ((64 + h * 16) ^ swz));
        bf16x8 kf10 = *(const bf16x8*)(bb + 2048 + li * 128 + ((h * 16) ^ swz));
        bf16x8 kf11 = *(const bf16x8*)(bb + 2048 + li * 128 + ((64 + h * 16) ^ swz));
        f32x4 s0 = {0.f,0.f,0.f,0.f}, s1 = {0.f,0.f,0.f,0.f};
        s0 = __builtin_amdgcn_mfma_f32_16x16x32_bf16(kf00, qf0, s0, 0, 0, 0);
        s0 = __builtin_amdgcn_mfma_f32_16x16x32_bf16(kf01, qf1, s0, 0, 0, 0);
        s1 = __builtin_amdgcn_mfma_f32_16x16x32_bf16(kf10, qf0, s1, 0, 0, 0);
        s1 = __builtin_amdgcn_mfma_f32_16x16x32_bf16(kf11, qf1, s1, 0, 0, 0);
        // V^T fragments: single b128 each
        const char* vb = bb + 4096;
        bf16x8 vf0 = *(const bf16x8*)(vb + (0 * 16 + li) * 64 + h * 16);
        bf16x8 vf1 = *(const bf16x8*)(vb + (1 * 16 + li) * 64 + h * 16);
        bf16x8 vf2 = *(const bf16x8*)(vb + (2 * 16 + li) * 64 + h * 16);
        bf16x8 vf3 = *(const bf16x8*)(vb + (3 * 16 + li) * 64 + h * 16);
        asm volatile("s_waitcnt lgkmcnt(0)" ::: "memory");  // LDS reads done before next barrier

        // online softmax with defer-max (THR = 8 in natural-log units)
        float tmax = fmaxf(fmaxf(fmaxf(s0[0], s0[1]), fmaxf(s0[2], s0[3])),
                           fmaxf(fmaxf(s1[0], s1[1]), fmaxf(s1[2], s1[3])));
        tmax = fmaxf(tmax, __shfl_xor(tmax, 16, 64));
        tmax = fmaxf(tmax, __shfl_xor(tmax, 32, 64));
        if (__any(tmax - m_run > 8.0f)) {
            const float m_new = fmaxf(m_run, tmax);
            const float sc = __expf(m_run - m_new);
            m_run = m_new;
            l_run *= sc;
            oacc0 *= sc; oacc1 *= sc; oacc2 *= sc; oacc3 *= sc;
        }
        bf16x8 pf;
        float psum = 0.f;
        #pragma unroll
        for (int r = 0; r < 4; ++r) {
            float p = __expf(s0[r] - m_run);
            psum += p; pf[r] = (__bf16)p;
        }
        #pragma unroll
        for (int r = 0; r < 4; ++r) {
            float p = __expf(s1[r] - m_run);
            psum += p; pf[4 + r] = (__bf16)p;
        }
        l_run += psum;
        oacc0 = __builtin_amdgcn_mfma_f32_16x16x32_bf16(vf0, pf, oacc0, 0, 0, 0);
        oacc1 = __builtin_amdgcn_mfma_f32_16x16x32_bf16(vf1, pf, oacc1, 0, 0, 0);
        oacc2 = __builtin_amdgcn_mfma_f32_16x16x32_bf16(vf2, pf, oacc2, 0, 0, 0);
        oacc3 = __builtin_amdgcn_mfma_f32_16x16x32_bf16(vf3, pf, oacc3, 0, 0, 0);
    };

    // prologue: tiles 0 and 1 in flight (4 outstanding vmem/thread)
    stage(0, 0);
    stage(1, 1);

    #pragma unroll 6
    for (int t = 0; t < NT - 2; ++t) {
        asm volatile("s_waitcnt vmcnt(2)" ::: "memory");   // tile t landed
        __builtin_amdgcn_s_barrier();                      // all waves' parts landed
        stage(t + 2, (t + 2) % 3);                         // overwrites t-1's buf (all reads done)
        body(t % 3);
    }
    asm volatile("s_waitcnt vmcnt(2)" ::: "memory");       // t = 30
    __builtin_amdgcn_s_barrier();
    body(0);
    asm volatile("s_waitcnt vmcnt(0)" ::: "memory");       // t = 31 (last: drain)
    __builtin_amdgcn_s_barrier();
    body(1);

    // finalize
    l_run += __shfl_xor(l_run, 16, 64);
    l_run += __shfl_xor(l_run, 32, 64);
    const float inv_l = 1.f / l_run;
    float* Ob = O + ((size_t)b * L_SEQ + qrow) * 64;
    f32x4 ov;
    #pragma unroll
    for (int r = 0; r < 4; ++r) ov[r] = oacc0[r] * inv_l;
    *(f32x4*)&Ob[0 * 16 + h * 4] = ov;
    #pragma unroll
    for (int r = 0; r < 4; ++r) ov[r] = oacc1[r] * inv_l;
    *(f32x4*)&Ob[1 * 16 + h * 4] = ov;
    #pragma unroll
    for (int r = 0; r < 4; ++r) ov[r] = oacc2[r] * inv_l;
    *(f32x4*)&Ob[2 * 16 + h * 4] = ov;
    #pragma unroll
    for (int r = 0; r < 4; ++r) ov[r] = oacc3[r] * inv_l;
    *(f32x4*)&Ob[3 * 16 + h * 4] = ov;
}

// ---------------------------------------------------------------------------
// Fallback (round-1 kernel, verified): used only if ws_size is too small.
// ---------------------------------------------------------------------------
__global__ __launch_bounds__(256) void sdpa_fwd_kernel(
    const float* __restrict__ Q, const float* __restrict__ K,
    const float* __restrict__ V, float* __restrict__ O)
{
    __shared__ __bf16 kt[KVBLK * KSTR];
    __shared__ __bf16 vt[D_HEAD * VSTR];

    const int tid  = threadIdx.x;
    const int lane = tid & 63;
    const int wave = tid >> 6;
    const int li   = lane & 15;
    const int h    = lane >> 4;

    const int b     = blockIdx.x >> 4;
    const int qtile = blockIdx.x & 15;
    const int qrow  = qtile * QBLK + wave * 16 + li;

    const float* Qb = Q + (size_t)b * L_SEQ * D_HEAD;
    const float* Kb = K + (size_t)b * L_SEQ * D_HEAD;
    const float* Vb = V + (size_t)b * L_SEQ * D_HEAD;

    bf16x8 qf[2];
    #pragma unroll
    for (int c = 0; c < 2; ++c) {
        #pragma unroll
        for (int hf = 0; hf < 2; ++hf) {
            f32x4 qv = *(const f32x4*)&Qb[(size_t)qrow * D_HEAD + c * 32 + hf * 16 + h * 4];
            #pragma unroll
            for (int j = 0; j < 4; ++j)
                qf[c][hf * 4 + j] = (__bf16)(qv[j] * 0.125f);
        }
    }

    f32x4 oacc[4];
    #pragma unroll
    for (int dc = 0; dc < 4; ++dc) oacc[dc] = (f32x4){0.f, 0.f, 0.f, 0.f};
    float m_run = -1e30f;
    float l_run = 0.f;

    for (int kv = 0; kv < L_SEQ; kv += KVBLK) {
        __syncthreads();
        #pragma unroll
        for (int it = 0; it < 2; ++it) {
            int idx = tid + it * 256;
            int j   = idx >> 4;
            int d4  = (idx & 15) << 2;
            f32x4 x = *(const f32x4*)&Kb[(size_t)(kv + j) * D_HEAD + d4];
            __bf16* dst = &kt[j * KSTR + d4];
            dst[0] = (__bf16)x[0]; dst[1] = (__bf16)x[1];
            dst[2] = (__bf16)x[2]; dst[3] = (__bf16)x[3];
        }
        #pragma unroll
        for (int it = 0; it < 2; ++it) {
            int idx = tid + it * 256;
            int j   = idx >> 4;
            int d4  = (idx & 15) << 2;
            f32x4 x = *(const f32x4*)&Vb[(size_t)(kv + j) * D_HEAD + d4];
            #pragma unroll
            for (int u = 0; u < 4; ++u)
                vt[(d4 + u) * VSTR + j] = (__bf16)x[u];
        }
        __syncthreads();

        f32x4 sacc[2];
        #pragma unroll
        for (int ch = 0; ch < 2; ++ch) {
            sacc[ch] = (f32x4){0.f, 0.f, 0.f, 0.f};
            #pragma unroll
            for (int c = 0; c < 2; ++c) {
                bf16x8 kf;
                #pragma unroll
                for (int hf = 0; hf < 2; ++hf) {
                    bf16x4 k4 = *(const bf16x4*)&kt[(ch * 16 + li) * KSTR + c * 32 + hf * 16 + h * 4];
                    #pragma unroll
                    for (int j = 0; j < 4; ++j) kf[hf * 4 + j] = k4[j];
                }
                sacc[ch] = __builtin_amdgcn_mfma_f32_16x16x32_bf16(kf, qf[c], sacc[ch], 0, 0, 0);
            }
        }

        float tmax = fmaxf(fmaxf(fmaxf(sacc[0][0], sacc[0][1]), fmaxf(sacc[0][2], sacc[0][3])),
                           fmaxf(fmaxf(sacc[1][0], sacc[1][1]), fmaxf(sacc[1][2], sacc[1][3])));
        tmax = fmaxf(tmax, __shfl_xor(tmax, 16, 64));
        tmax = fmaxf(tmax, __shfl_xor(tmax, 32, 64));
        const float m_new = fmaxf(m_run, tmax);
        const float scale = __expf(m_run - m_new);
        m_run = m_new;
        l_run *= scale;
        #pragma unroll
        for (int dc = 0; dc < 4; ++dc) {
            #pragma unroll
            for (int r = 0; r < 4; ++r) oacc[dc][r] *= scale;
        }

        bf16x8 pf;
        float psum = 0.f;
        #pragma unroll
        for (int ch = 0; ch < 2; ++ch) {
            #pragma unroll
            for (int r = 0; r < 4; ++r) {
                float p = __expf(sacc[ch][r] - m_new);
                psum += p;
                pf[ch * 4 + r] = (__bf16)p;
            }
        }
        l_run += psum;

        #pragma unroll
        for (int dc = 0; dc < 4; ++dc) {
            bf16x8 vf;
            #pragma unroll
            for (int hf = 0; hf < 2; ++hf) {
                bf16x4 v4 = *(const bf16x4*)&vt[(dc * 16 + li) * VSTR + hf * 16 + h * 4];
                #pragma unroll
                for (int j = 0; j < 4; ++j) vf[hf * 4 + j] = v4[j];
            }
            oacc[dc] = __builtin_amdgcn_mfma_f32_16x16x32_bf16(vf, pf, oacc[dc], 0, 0, 0);
        }
    }

    l_run += __shfl_xor(l_run, 16, 64);
    l_run += __shfl_xor(l_run, 32, 64);
    const float inv_l = 1.f / l_run;

    float* Ob = O + ((size_t)b * L_SEQ + qrow) * D_HEAD;
    #pragma unroll
    for (int dc = 0; dc < 4; ++dc) {
        f32x4 ov;
        #pragma unroll
        for (int r = 0; r < 4; ++r) ov[r] = oacc[dc][r] * inv_l;
        *(f32x4*)&Ob[dc * 16 + h * 4] = ov;
    }
}

extern "C" void kernel_launch(void* const* d_in, const int* in_sizes, int n_in,
                              void* d_out, int out_size, void* d_ws, size_t ws_size,
                              hipStream_t stream) {
    const float* q = (const float*)d_in[0];
    const float* k = (const float*)d_in[1];
    const float* v = (const float*)d_in[2];
    float* o = (float*)d_out;

    const size_t PRE = (size_t)64 * L_SEQ * 64 * sizeof(__bf16);   // 8 MB per array
    if (ws_size >= 3 * PRE) {
        __bf16* Qp = (__bf16*)d_ws;
        __bf16* Kp = (__bf16*)((char*)d_ws + PRE);
        __bf16* Vp = (__bf16*)((char*)d_ws + 2 * PRE);
        sdpa_prep<<<dim3(12288), dim3(256), 0, stream>>>(q, k, v, Qp, Kp, Vp);
        sdpa_main<<<dim3(1024), dim3(256), 0, stream>>>(Qp, Kp, Vp, o);
    } else {
        sdpa_fwd_kernel<<<dim3(1024), dim3(256), 0, stream>>>(q, k, v, o);
    }
}

// Round 3
// 48.395 us; speedup vs baseline: 1.5800x; 1.1298x over previous
//
#include <hip/hip_runtime.h>
#include <hip/hip_bf16.h>

#define L_SEQ 1024
#define D_HEAD 64
#define NT 32          // number of 32-row KV tiles
#define KVBLK 32
#define KSTR 72
#define VSTR 36

typedef __attribute__((ext_vector_type(8))) __bf16 bf16x8;
typedef __attribute__((ext_vector_type(4))) __bf16 bf16x4;
typedef __attribute__((ext_vector_type(4))) float f32x4;
typedef unsigned int u32;

#define STAGE16(gsrc, ldst)                                                     \
  __builtin_amdgcn_global_load_lds(                                             \
      (const __attribute__((address_space(1))) u32*)(gsrc),                     \
      (__attribute__((address_space(3))) u32*)(ldst), 16, 0, 0)

// ---------------------------------------------------------------------------
// Pre-pass: K -> bf16 fragment-permuted + XOR-swizzled tile images;
//           V -> bf16 V^T tile images (transposed via LDS, coalesced writes).
// K_pre: [row][c''] c'' = (c32*32 + h*8 + hf*4 + j) ^ ((row&7)*8), stride 64
// V_pre: per 32-row tile: [d][cp(k)], cp = vh*8 + vhf*4 + vj  (k = vhf*16+vh*4+vj)
// ---------------------------------------------------------------------------
__global__ __launch_bounds__(256) void sdpa_prep(
    const float* __restrict__ K, const float* __restrict__ V,
    __bf16* __restrict__ Kp, __bf16* __restrict__ Vp)
{
    __shared__ float vt[32][68];   // V tile transpose buffer (padded)
    const int tid = threadIdx.x;

    if (blockIdx.x < 4096) {
        // ---- K path: 1M quads
        const int gid = blockIdx.x * 256 + tid;
        const int row = gid >> 4;               // global row (b*1024 + r)
        const int d4  = (gid & 15) << 2;
        f32x4 x = *(const f32x4*)&K[(size_t)row * 64 + d4];
        const int c32 = d4 >> 5, rem = d4 & 31, hf = rem >> 4, h = (rem & 15) >> 2;
        const int cp = ((c32 * 32 + h * 8) ^ ((row & 7) * 8)) + hf * 4;
        bf16x4 o;
        #pragma unroll
        for (int u = 0; u < 4; ++u) o[u] = (__bf16)x[u];
        *(bf16x4*)&Kp[(size_t)row * 64 + cp] = o;
    } else {
        // ---- V path: one 32x64 tile per block, transpose via LDS
        const int T = blockIdx.x - 4096;        // 0..2047
        const float* src = V + (size_t)T * 2048;
        #pragma unroll
        for (int i = 0; i < 2; ++i) {
            int idx = tid + i * 256;
            int r   = idx >> 4;
            int d4  = (idx & 15) << 2;
            f32x4 x = *(const f32x4*)&src[r * 64 + d4];
            vt[r][d4 + 0] = x[0]; vt[r][d4 + 1] = x[1];
            vt[r][d4 + 2] = x[2]; vt[r][d4 + 3] = x[3];
        }
        __syncthreads();
        #pragma unroll
        for (int i = 0; i < 2; ++i) {
            int w = tid + i * 256;
            int d = w >> 3, comb = w & 7, vh = comb >> 1, vhf = comb & 1;
            bf16x4 o;
            #pragma unroll
            for (int vj = 0; vj < 4; ++vj)
                o[vj] = (__bf16)vt[vhf * 16 + vh * 4 + vj][d];
            *(bf16x4*)&Vp[(size_t)T * 2048 + d * 32 + vh * 8 + vhf * 4] = o;
        }
    }
}

// ---------------------------------------------------------------------------
// Main: 512 blocks x 4 waves; each wave owns 32 q rows (2 q-blocks of 16) so
// K/V LDS fragments are read once and reused. Triple-buffered LDS,
// global_load_lds staging, counted vmcnt(2), 1 barrier/iter, defer-max.
// ---------------------------------------------------------------------------
__global__ __launch_bounds__(256) void sdpa_main(
    const float* __restrict__ Q, const __bf16* __restrict__ Kp,
    const __bf16* __restrict__ Vp, float* __restrict__ O)
{
    __shared__ __align__(16) char ldsraw[3 * 8192];   // 3 x (K 4KB + V 4KB)

    const int tid  = threadIdx.x;
    const int lane = tid & 63;
    const int wave = tid >> 6;
    const int li   = lane & 15;
    const int h    = lane >> 4;

    // XCD-chunked swizzle: 512 blocks, 64 per XCD -> 8 batches per XCD L2.
    const int wg = blockIdx.x;
    const int lb = (wg & 7) * 64 + (wg >> 3);
    const int b  = lb >> 3;          // batch
    const int qt = lb & 7;           // 128-row q-tile
    const int q0 = qt * 128 + wave * 16 + li;
    // q-block1 rows are q0 + 64

    const float*  Qb = Q  + (size_t)b * L_SEQ * 64;
    const char*   Kb = (const char*)(Kp + (size_t)b * L_SEQ * 64);
    const char*   Vb = (const char*)(Vp + (size_t)b * L_SEQ * 64);

    // ---- Q fragments (direct f32 load, fold 1/temperature)
    bf16x8 q0f[2], q1f[2];
    #pragma unroll
    for (int c = 0; c < 2; ++c) {
        #pragma unroll
        for (int hf = 0; hf < 2; ++hf) {
            f32x4 a = *(const f32x4*)&Qb[(size_t)q0 * 64 + c * 32 + hf * 16 + h * 4];
            f32x4 bq = *(const f32x4*)&Qb[(size_t)(q0 + 64) * 64 + c * 32 + hf * 16 + h * 4];
            #pragma unroll
            for (int j = 0; j < 4; ++j) {
                q0f[c][hf * 4 + j] = (__bf16)(a[j] * 0.125f);
                q1f[c][hf * 4 + j] = (__bf16)(bq[j] * 0.125f);
            }
        }
    }

    f32x4 o0[4], o1[4];
    #pragma unroll
    for (int dc = 0; dc < 4; ++dc) {
        o0[dc] = (f32x4){0.f,0.f,0.f,0.f};
        o1[dc] = (f32x4){0.f,0.f,0.f,0.f};
    }
    float m0 = -1e30f, l0 = 0.f, m1 = -1e30f, l1 = 0.f;

    auto stage = [&](int t, int bi) {
        const size_t go = (size_t)t * 4096 + (size_t)wave * 1024 + (size_t)(lane << 4);
        STAGE16(Kb + go, ldsraw + bi * 8192 + wave * 1024);
        STAGE16(Vb + go, ldsraw + bi * 8192 + 4096 + wave * 1024);
    };

    auto body = [&](int bi) {
        const char* bb  = ldsraw + bi * 8192;
        const int   swz = (li & 7) << 4;
        // K fragments (shared by both q-blocks)
        bf16x8 kf00 = *(const bf16x8*)(bb + li * 128 + ((h * 16) ^ swz));
        bf16x8 kf01 = *(const bf16x8*)(bb + li * 128 + ((64 + h * 16) ^ swz));
        bf16x8 kf10 = *(const bf16x8*)(bb + 2048 + li * 128 + ((h * 16) ^ swz));
        bf16x8 kf11 = *(const bf16x8*)(bb + 2048 + li * 128 + ((64 + h * 16) ^ swz));
        f32x4 s00 = {0.f,0.f,0.f,0.f}, s01 = {0.f,0.f,0.f,0.f};
        f32x4 s10 = {0.f,0.f,0.f,0.f}, s11 = {0.f,0.f,0.f,0.f};
        __builtin_amdgcn_s_setprio(1);
        s00 = __builtin_amdgcn_mfma_f32_16x16x32_bf16(kf00, q0f[0], s00, 0, 0, 0);
        s00 = __builtin_amdgcn_mfma_f32_16x16x32_bf16(kf01, q0f[1], s00, 0, 0, 0);
        s01 = __builtin_amdgcn_mfma_f32_16x16x32_bf16(kf10, q0f[0], s01, 0, 0, 0);
        s01 = __builtin_amdgcn_mfma_f32_16x16x32_bf16(kf11, q0f[1], s01, 0, 0, 0);
        s10 = __builtin_amdgcn_mfma_f32_16x16x32_bf16(kf00, q1f[0], s10, 0, 0, 0);
        s10 = __builtin_amdgcn_mfma_f32_16x16x32_bf16(kf01, q1f[1], s10, 0, 0, 0);
        s11 = __builtin_amdgcn_mfma_f32_16x16x32_bf16(kf10, q1f[0], s11, 0, 0, 0);
        s11 = __builtin_amdgcn_mfma_f32_16x16x32_bf16(kf11, q1f[1], s11, 0, 0, 0);
        __builtin_amdgcn_s_setprio(0);
        // V^T fragments (shared)
        const char* vb = bb + 4096;
        bf16x8 vf0 = *(const bf16x8*)(vb + (0 * 16 + li) * 64 + h * 16);
        bf16x8 vf1 = *(const bf16x8*)(vb + (1 * 16 + li) * 64 + h * 16);
        bf16x8 vf2 = *(const bf16x8*)(vb + (2 * 16 + li) * 64 + h * 16);
        bf16x8 vf3 = *(const bf16x8*)(vb + (3 * 16 + li) * 64 + h * 16);
        asm volatile("s_waitcnt lgkmcnt(0)" ::: "memory");  // all LDS reads drained pre-barrier

        // ---- softmax q-block0
        float t0 = fmaxf(fmaxf(fmaxf(s00[0], s00[1]), fmaxf(s00[2], s00[3])),
                         fmaxf(fmaxf(s01[0], s01[1]), fmaxf(s01[2], s01[3])));
        t0 = fmaxf(t0, __shfl_xor(t0, 16, 64));
        t0 = fmaxf(t0, __shfl_xor(t0, 32, 64));
        if (__any(t0 - m0 > 8.0f)) {
            const float mn = fmaxf(m0, t0);
            const float sc = __expf(m0 - mn);
            m0 = mn; l0 *= sc;
            #pragma unroll
            for (int dc = 0; dc < 4; ++dc) o0[dc] *= sc;
        }
        bf16x8 pf0;
        float ps0 = 0.f;
        #pragma unroll
        for (int r = 0; r < 4; ++r) { float p = __expf(s00[r] - m0); ps0 += p; pf0[r] = (__bf16)p; }
        #pragma unroll
        for (int r = 0; r < 4; ++r) { float p = __expf(s01[r] - m0); ps0 += p; pf0[4 + r] = (__bf16)p; }
        l0 += ps0;

        // ---- softmax q-block1
        float t1 = fmaxf(fmaxf(fmaxf(s10[0], s10[1]), fmaxf(s10[2], s10[3])),
                         fmaxf(fmaxf(s11[0], s11[1]), fmaxf(s11[2], s11[3])));
        t1 = fmaxf(t1, __shfl_xor(t1, 16, 64));
        t1 = fmaxf(t1, __shfl_xor(t1, 32, 64));
        if (__any(t1 - m1 > 8.0f)) {
            const float mn = fmaxf(m1, t1);
            const float sc = __expf(m1 - mn);
            m1 = mn; l1 *= sc;
            #pragma unroll
            for (int dc = 0; dc < 4; ++dc) o1[dc] *= sc;
        }
        bf16x8 pf1;
        float ps1 = 0.f;
        #pragma unroll
        for (int r = 0; r < 4; ++r) { float p = __expf(s10[r] - m1); ps1 += p; pf1[r] = (__bf16)p; }
        #pragma unroll
        for (int r = 0; r < 4; ++r) { float p = __expf(s11[r] - m1); ps1 += p; pf1[4 + r] = (__bf16)p; }
        l1 += ps1;

        __builtin_amdgcn_s_setprio(1);
        o0[0] = __builtin_amdgcn_mfma_f32_16x16x32_bf16(vf0, pf0, o0[0], 0, 0, 0);
        o0[1] = __builtin_amdgcn_mfma_f32_16x16x32_bf16(vf1, pf0, o0[1], 0, 0, 0);
        o0[2] = __builtin_amdgcn_mfma_f32_16x16x32_bf16(vf2, pf0, o0[2], 0, 0, 0);
        o0[3] = __builtin_amdgcn_mfma_f32_16x16x32_bf16(vf3, pf0, o0[3], 0, 0, 0);
        o1[0] = __builtin_amdgcn_mfma_f32_16x16x32_bf16(vf0, pf1, o1[0], 0, 0, 0);
        o1[1] = __builtin_amdgcn_mfma_f32_16x16x32_bf16(vf1, pf1, o1[1], 0, 0, 0);
        o1[2] = __builtin_amdgcn_mfma_f32_16x16x32_bf16(vf2, pf1, o1[2], 0, 0, 0);
        o1[3] = __builtin_amdgcn_mfma_f32_16x16x32_bf16(vf3, pf1, o1[3], 0, 0, 0);
        __builtin_amdgcn_s_setprio(0);
    };

    // prologue: tiles 0 and 1 in flight
    stage(0, 0);
    stage(1, 1);

    #pragma unroll 6
    for (int t = 0; t < NT - 2; ++t) {
        asm volatile("s_waitcnt vmcnt(2)" ::: "memory");   // tile t landed
        __builtin_amdgcn_s_barrier();
        stage(t + 2, (t + 2) % 3);
        body(t % 3);
    }
    asm volatile("s_waitcnt vmcnt(2)" ::: "memory");
    __builtin_amdgcn_s_barrier();
    body(0);
    asm volatile("s_waitcnt vmcnt(0)" ::: "memory");
    __builtin_amdgcn_s_barrier();
    body(1);

    // ---- finalize
    l0 += __shfl_xor(l0, 16, 64);
    l0 += __shfl_xor(l0, 32, 64);
    l1 += __shfl_xor(l1, 16, 64);
    l1 += __shfl_xor(l1, 32, 64);
    const float il0 = 1.f / l0, il1 = 1.f / l1;
    float* Ob0 = O + ((size_t)b * L_SEQ + q0) * 64;
    float* Ob1 = Ob0 + 64 * 64;
    #pragma unroll
    for (int dc = 0; dc < 4; ++dc) {
        f32x4 ov;
        #pragma unroll
        for (int r = 0; r < 4; ++r) ov[r] = o0[dc][r] * il0;
        *(f32x4*)&Ob0[dc * 16 + h * 4] = ov;
    }
    #pragma unroll
    for (int dc = 0; dc < 4; ++dc) {
        f32x4 ov;
        #pragma unroll
        for (int r = 0; r < 4; ++r) ov[r] = o1[dc][r] * il1;
        *(f32x4*)&Ob1[dc * 16 + h * 4] = ov;
    }
}

// ---------------------------------------------------------------------------
// Fallback (round-1 kernel, verified): used only if ws_size is too small.
// ---------------------------------------------------------------------------
__global__ __launch_bounds__(256) void sdpa_fwd_kernel(
    const float* __restrict__ Q, const float* __restrict__ K,
    const float* __restrict__ V, float* __restrict__ O)
{
    __shared__ __bf16 kt[KVBLK * KSTR];
    __shared__ __bf16 vt[D_HEAD * VSTR];

    const int tid  = threadIdx.x;
    const int lane = tid & 63;
    const int wave = tid >> 6;
    const int li   = lane & 15;
    const int h    = lane >> 4;

    const int b     = blockIdx.x >> 4;
    const int qtile = blockIdx.x & 15;
    const int qrow  = qtile * 64 + wave * 16 + li;

    const float* Qb = Q + (size_t)b * L_SEQ * D_HEAD;
    const float* Kb = K + (size_t)b * L_SEQ * D_HEAD;
    const float* Vb = V + (size_t)b * L_SEQ * D_HEAD;

    bf16x8 qf[2];
    #pragma unroll
    for (int c = 0; c < 2; ++c) {
        #pragma unroll
        for (int hf = 0; hf < 2; ++hf) {
            f32x4 qv = *(const f32x4*)&Qb[(size_t)qrow * D_HEAD + c * 32 + hf * 16 + h * 4];
            #pragma unroll
            for (int j = 0; j < 4; ++j)
                qf[c][hf * 4 + j] = (__bf16)(qv[j] * 0.125f);
        }
    }

    f32x4 oacc[4];
    #pragma unroll
    for (int dc = 0; dc < 4; ++dc) oacc[dc] = (f32x4){0.f, 0.f, 0.f, 0.f};
    float m_run = -1e30f;
    float l_run = 0.f;

    for (int kv = 0; kv < L_SEQ; kv += KVBLK) {
        __syncthreads();
        #pragma unroll
        for (int it = 0; it < 2; ++it) {
            int idx = tid + it * 256;
            int j   = idx >> 4;
            int d4  = (idx & 15) << 2;
            f32x4 x = *(const f32x4*)&Kb[(size_t)(kv + j) * D_HEAD + d4];
            __bf16* dst = &kt[j * KSTR + d4];
            dst[0] = (__bf16)x[0]; dst[1] = (__bf16)x[1];
            dst[2] = (__bf16)x[2]; dst[3] = (__bf16)x[3];
        }
        #pragma unroll
        for (int it = 0; it < 2; ++it) {
            int idx = tid + it * 256;
            int j   = idx >> 4;
            int d4  = (idx & 15) << 2;
            f32x4 x = *(const f32x4*)&Vb[(size_t)(kv + j) * D_HEAD + d4];
            #pragma unroll
            for (int u = 0; u < 4; ++u)
                vt[(d4 + u) * VSTR + j] = (__bf16)x[u];
        }
        __syncthreads();

        f32x4 sacc[2];
        #pragma unroll
        for (int ch = 0; ch < 2; ++ch) {
            sacc[ch] = (f32x4){0.f, 0.f, 0.f, 0.f};
            #pragma unroll
            for (int c = 0; c < 2; ++c) {
                bf16x8 kf;
                #pragma unroll
                for (int hf = 0; hf < 2; ++hf) {
                    bf16x4 k4 = *(const bf16x4*)&kt[(ch * 16 + li) * KSTR + c * 32 + hf * 16 + h * 4];
                    #pragma unroll
                    for (int j = 0; j < 4; ++j) kf[hf * 4 + j] = k4[j];
                }
                sacc[ch] = __builtin_amdgcn_mfma_f32_16x16x32_bf16(kf, qf[c], sacc[ch], 0, 0, 0);
            }
        }

        float tmax = fmaxf(fmaxf(fmaxf(sacc[0][0], sacc[0][1]), fmaxf(sacc[0][2], sacc[0][3])),
                           fmaxf(fmaxf(sacc[1][0], sacc[1][1]), fmaxf(sacc[1][2], sacc[1][3])));
        tmax = fmaxf(tmax, __shfl_xor(tmax, 16, 64));
        tmax = fmaxf(tmax, __shfl_xor(tmax, 32, 64));
        const float m_new = fmaxf(m_run, tmax);
        const float scale = __expf(m_run - m_new);
        m_run = m_new;
        l_run *= scale;
        #pragma unroll
        for (int dc = 0; dc < 4; ++dc) {
            #pragma unroll
            for (int r = 0; r < 4; ++r) oacc[dc][r] *= scale;
        }

        bf16x8 pf;
        float psum = 0.f;
        #pragma unroll
        for (int ch = 0; ch < 2; ++ch) {
            #pragma unroll
            for (int r = 0; r < 4; ++r) {
                float p = __expf(sacc[ch][r] - m_new);
                psum += p;
                pf[ch * 4 + r] = (__bf16)p;
            }
        }
        l_run += psum;

        #pragma unroll
        for (int dc = 0; dc < 4; ++dc) {
            bf16x8 vf;
            #pragma unroll
            for (int hf = 0; hf < 2; ++hf) {
                bf16x4 v4 = *(const bf16x4*)&vt[(dc * 16 + li) * VSTR + hf * 16 + h * 4];
                #pragma unroll
                for (int j = 0; j < 4; ++j) vf[hf * 4 + j] = v4[j];
            }
            oacc[dc] = __builtin_amdgcn_mfma_f32_16x16x32_bf16(vf, pf, oacc[dc], 0, 0, 0);
        }
    }

    l_run += __shfl_xor(l_run, 16, 64);
    l_run += __shfl_xor(l_run, 32, 64);
    const float inv_l = 1.f / l_run;

    float* Ob = O + ((size_t)b * L_SEQ + qrow) * D_HEAD;
    #pragma unroll
    for (int dc = 0; dc < 4; ++dc) {
        f32x4 ov;
        #pragma unroll
        for (int r = 0; r < 4; ++r) ov[r] = oacc[dc][r] * inv_l;
        *(f32x4*)&Ob[dc * 16 + h * 4] = ov;
    }
}

extern "C" void kernel_launch(void* const* d_in, const int* in_sizes, int n_in,
                              void* d_out, int out_size, void* d_ws, size_t ws_size,
                              hipStream_t stream) {
    const float* q = (const float*)d_in[0];
    const float* k = (const float*)d_in[1];
    const float* v = (const float*)d_in[2];
    float* o = (float*)d_out;

    const size_t PRE = (size_t)64 * L_SEQ * 64 * sizeof(__bf16);   // 8.4 MB per array
    if (ws_size >= 2 * PRE) {
        __bf16* Kp = (__bf16*)d_ws;
        __bf16* Vp = (__bf16*)((char*)d_ws + PRE);
        sdpa_prep<<<dim3(6144), dim3(256), 0, stream>>>(k, v, Kp, Vp);
        sdpa_main<<<dim3(512), dim3(256), 0, stream>>>(q, Kp, Vp, o);
    } else {
        sdpa_fwd_kernel<<<dim3(1024), dim3(256), 0, stream>>>(q, k, v, o);
    }
}